// Round 4
// baseline (603.946 us; speedup 1.0000x reference)
//
#include <hip/hip_runtime.h>

typedef __attribute__((ext_vector_type(8))) short bf16x8;
typedef __attribute__((ext_vector_type(4))) float f32x4;

#define DEVFN __device__ __forceinline__

DEVFN short f2bf(float f) {
    union { float f; unsigned u; } v; v.f = f;
    unsigned r = (v.u + 0x7FFFu + ((v.u >> 16) & 1u)) >> 16;
    return (short)(unsigned short)r;
}
DEVFN float bf2f(short h) {
    union { unsigned u; float f; } v; v.u = ((unsigned)(unsigned short)h) << 16;
    return v.f;
}
DEVFN float2 bfpair(unsigned u) {
    union { unsigned v; float f; } a, b;
    a.v = u << 16; b.v = u & 0xFFFF0000u;
    float2 r; r.x = a.f; r.y = b.f; return r;
}
DEVFN unsigned packbf(float a, float b) {
    return (unsigned)(unsigned short)f2bf(a) | ((unsigned)(unsigned short)f2bf(b) << 16);
}

// ---------------- prep kernels ----------------

__global__ __launch_bounds__(128) void build_w1p_k(
    const float* __restrict__ Wb, const float* __restrict__ We1,
    const float* __restrict__ bb, const float* __restrict__ be1,
    float* __restrict__ W1p, float* __restrict__ b1p)
{
    int j = threadIdx.x;
    const float* B = We1 + 128 * 128;
    int i = blockIdx.x;
    if (i < 200) {
        float a = 0.f;
        for (int m = 0; m < 128; m++) a += Wb[i * 128 + m] * B[m * 128 + j];
        W1p[i * 128 + j] = a;
    } else {
        float a = be1[j];
        for (int m = 0; m < 128; m++) a += bb[m] * B[m * 128 + j];
        b1p[j] = a;
    }
}

__global__ __launch_bounds__(128) void build_tab_k(
    const float* __restrict__ W1p, const float* __restrict__ b1p,
    short* __restrict__ tab)
{
    int i = blockIdx.x;   // 0..1024
    int c = blockIdx.y;   // 0..3
    int j = threadIdx.x;
    float t = (float)i * (1.0f / 1024.0f);
    float acc = (c == 0) ? b1p[j] : 0.f;
    int kc = (int)(t * 49.f + 0.5f);
    for (int dk = -6; dk <= 6; dk++) {
        int k = kc + dk;
        if (k >= 0 && k < 50) {
            float d = t - (float)k * (1.f / 49.f);
            float g = expf(-1250.f * d * d);
            acc += g * W1p[(c * 50 + k) * 128 + j];
        }
    }
    tab[((size_t)(c * 1025 + i)) * 128 + j] = f2bf(acc);
}

__global__ __launch_bounds__(256) void fold_plain_k(
    const float* __restrict__ W0, const float* __restrict__ W1,
    const float* __restrict__ W2, const float* __restrict__ W3,
    short* __restrict__ O0, short* __restrict__ O1,
    short* __restrict__ O2, short* __restrict__ O3)
{
    const float* W = (blockIdx.y == 0) ? W0 : (blockIdx.y == 1) ? W1 : (blockIdx.y == 2) ? W2 : W3;
    short* O = (blockIdx.y == 0) ? O0 : (blockIdx.y == 1) ? O1 : (blockIdx.y == 2) ? O2 : O3;
    int idx = blockIdx.x * 256 + threadIdx.x;
    int n = idx >> 8, ks = (idx >> 6) & 3, lane = idx & 63;
    int k8 = ks * 32 + (lane >> 4) * 8;
    int col = n * 16 + (lane & 15);
    bf16x8 fv;
    #pragma unroll
    for (int i2 = 0; i2 < 8; i2++) fv[i2] = f2bf(W[(k8 + i2) * 128 + col]);
    *(bf16x8*)(O + (size_t)idx * 8) = fv;
}

__global__ __launch_bounds__(256) void fold_k(
    const float* __restrict__ W, const float* __restrict__ bias,
    const float* __restrict__ statsG, const float* __restrict__ gamma,
    const float* __restrict__ beta, float invNs,
    short* __restrict__ Bp, float* __restrict__ biasOut)
{
    __shared__ float sS[128], sT[128];
    int tid = threadIdx.x;
    if (tid < 128) {
        float sum = 0.f, sq = 0.f;
        for (int r = 0; r < 16; r++) {
            sum += statsG[r * 256 + tid];
            sq  += statsG[r * 256 + 128 + tid];
        }
        float m = sum * invNs;
        float var = sq * invNs - m * m;
        float rs = rsqrtf(var + 1e-5f);
        float s = rs * gamma[tid];
        float t = beta[tid] - m * s;
        sS[tid] = s; sT[tid] = t;
    }
    __syncthreads();
    if (blockIdx.x == 0 && tid < 128) {
        float b = bias[tid];
        for (int k = 0; k < 128; k++) b += sT[k] * W[k * 128 + tid];
        biasOut[tid] = b;
    }
    int idx = blockIdx.x * 256 + tid;
    int n = idx >> 8, ks = (idx >> 6) & 3, lane = idx & 63;
    int k8 = ks * 32 + (lane >> 4) * 8;
    int col = n * 16 + (lane & 15);
    bf16x8 fv;
    #pragma unroll
    for (int i2 = 0; i2 < 8; i2++)
        fv[i2] = f2bf(sS[k8 + i2] * W[(k8 + i2) * 128 + col]);
    *(bf16x8*)(Bp + (size_t)idx * 8) = fv;
}

// ---------------- x -> bf16 cast ----------------
__global__ __launch_bounds__(256) void cast_k(
    const float* __restrict__ x, unsigned* __restrict__ xb2, int n8)
{
    int i = blockIdx.x * 256 + threadIdx.x;
    if (i >= n8) return;
    const float4* p = (const float4*)x + (size_t)i * 2;
    float4 a = p[0], b = p[1];
    uint4 o;
    o.x = packbf(a.x, a.y); o.y = packbf(a.z, a.w);
    o.z = packbf(b.x, b.y); o.w = packbf(b.z, b.w);
    ((uint4*)xb2)[i] = o;
}

// ---------------- counting sort by dst ----------------

__global__ __launch_bounds__(256) void hist_k(
    const int* __restrict__ dstI, int* __restrict__ cnt, int E)
{
    int e = blockIdx.x * 256 + threadIdx.x;
    if (e < E) atomicAdd(&cnt[dstI[e]], 1);
}

__global__ __launch_bounds__(256) void scan1_k(
    const int* __restrict__ cnt, int Nn, int* __restrict__ posE, int* __restrict__ bsum)
{
    __shared__ int s[256];
    int t = threadIdx.x, g = blockIdx.x * 256 + t;
    int v = (g < Nn) ? cnt[g] : 0;
    s[t] = v;
    __syncthreads();
    for (int off = 1; off < 256; off <<= 1) {
        int u = (t >= off) ? s[t - off] : 0;
        __syncthreads();
        s[t] += u;
        __syncthreads();
    }
    if (g < Nn) posE[g] = s[t] - v;
    if (t == 255) bsum[blockIdx.x] = s[255];
}

__global__ __launch_bounds__(256) void scan2_k(int* __restrict__ bsum, int nb)
{
    __shared__ int s[256];
    int t = threadIdx.x;
    int v = (t < nb) ? bsum[t] : 0;
    s[t] = v;
    __syncthreads();
    for (int off = 1; off < 256; off <<= 1) {
        int u = (t >= off) ? s[t - off] : 0;
        __syncthreads();
        s[t] += u;
        __syncthreads();
    }
    if (t < nb) bsum[t] = s[t] - v;
}

__global__ __launch_bounds__(256) void fix_k(
    const int* __restrict__ posE, const int* __restrict__ bsum,
    int* __restrict__ pos2, int Nn)
{
    int id = blockIdx.x * 256 + threadIdx.x;
    if (id < Nn) pos2[id] = posE[id] + bsum[id >> 8];
}

__global__ __launch_bounds__(256) void scat_k(
    const int* __restrict__ srcI, const int* __restrict__ dstI,
    const float4* __restrict__ ea4, int* __restrict__ pos2,
    int* __restrict__ sSrc, int* __restrict__ sDst,
    float* __restrict__ scf, float4* __restrict__ sEa, int E)
{
    int e = blockIdx.x * 256 + threadIdx.x;
    if (e >= E) return;
    int d = dstI[e];
    int p = atomicAdd(&pos2[d], 1);
    sSrc[p] = srcI[e];
    sDst[p] = d;
    float4 ev = ea4[e];
    sEa[p] = ev;
    scf[p] = cosf(1.57079632679f * ev.w);
}

// ---------------- edge pass 1 (sorted order, 2 cols/lane) ----------------
__global__ __launch_bounds__(256) void edge_z1_k(
    const short* __restrict__ xs1b, const short* __restrict__ xt1b,
    const short* __restrict__ tab,
    const int* __restrict__ sSrc, const int* __restrict__ sDst,
    const float4* __restrict__ sEa,
    short* __restrict__ z1, float* __restrict__ stats, int Etot)
{
    int tid = threadIdx.x, wave = tid >> 6, lane = tid & 63;
    int e0 = blockIdx.x * 256 + wave * 64;
    const unsigned* xs2 = (const unsigned*)xs1b;
    const unsigned* xt2 = (const unsigned*)xt1b;
    const unsigned* tb2 = (const unsigned*)tab;
    unsigned* z2 = (unsigned*)z1;

    int eL = e0 + lane;
    int myS = 0, myD = 0;
    float4 myE = {0.f, 0.f, 0.f, 0.f};
    if (eL < Etot) { myS = sSrc[eL]; myD = sDst[eL]; myE = sEa[eL]; }

    float s0 = 0.f, q0 = 0.f, s1 = 0.f, q1 = 0.f;
    int ni = Etot - e0; if (ni > 64) ni = 64;
    for (int i = 0; i < ni; i++) {
        int s = __shfl(myS, i), d = __shfl(myD, i);
        float tv[4];
        tv[0] = __shfl(myE.x, i); tv[1] = __shfl(myE.y, i);
        tv[2] = __shfl(myE.z, i); tv[3] = __shfl(myE.w, i);
        float2 xs = bfpair(xs2[(size_t)s * 64 + lane]);
        float2 xt = bfpair(xt2[(size_t)d * 64 + lane]);
        float p0 = xs.x + xt.x, p1 = xs.y + xt.y;
        #pragma unroll
        for (int c = 0; c < 4; c++) {
            float u = tv[c] * 1024.f;
            int i0 = (int)u;
            if (i0 > 1023) i0 = 1023;
            if (i0 < 0) i0 = 0;
            float f = u - (float)i0;
            size_t base = (size_t)(c * 1025 + i0) * 64 + lane;
            float2 v0 = bfpair(tb2[base]);
            float2 v1 = bfpair(tb2[base + 64]);
            p0 += v0.x + f * (v1.x - v0.x);
            p1 += v0.y + f * (v1.y - v0.y);
        }
        float z0 = p0 >= 0.f ? p0 : 0.01f * p0;
        float z1v = p1 >= 0.f ? p1 : 0.01f * p1;
        z2[(size_t)(e0 + i) * 64 + lane] = packbf(z0, z1v);
        s0 += z0; q0 += z0 * z0; s1 += z1v; q1 += z1v * z1v;
    }

    __shared__ float lS[128], lQ[128];
    if (tid < 128) { lS[tid] = 0.f; lQ[tid] = 0.f; }
    __syncthreads();
    atomicAdd(&lS[2 * lane], s0);     atomicAdd(&lS[2 * lane + 1], s1);
    atomicAdd(&lQ[2 * lane], q0);     atomicAdd(&lQ[2 * lane + 1], q1);
    __syncthreads();
    if (tid < 128) {
        int rep = blockIdx.x & 15;
        atomicAdd(&stats[rep * 256 + tid], lS[tid]);
        atomicAdd(&stats[rep * 256 + 128 + tid], lQ[tid]);
    }
}

// ---------------- persistent tall-skinny MFMA GEMM ----------------
// A (Mx128 bf16) @ B'(128x128), B staged in LDS once, barrier-free chunk loop
// with next-chunk A prefetch. 64 rows per chunk per block.
// EPI 0: out=bf16 val (xd);  out2 = bf16 v*val (zacc init)
// EPI 1: out=bf16 val
// EPI 2: z=lrelu(val); out bf16; BN stats (register-accumulated)
// EPI 3: dst-sorted scatter: run-merged pk_add_bf16(zacc[dst], cf*val*xd[src])
// EPI 4: out fp32 = val + xres
template<int EPI>
__global__ __launch_bounds__(256) void pgemm_k(
    const short* __restrict__ A, int M, int nch,
    const short* __restrict__ Bp, const float* __restrict__ bias,
    void* __restrict__ out, short* __restrict__ out2,
    float* __restrict__ stats,
    const short* __restrict__ xdb, short* __restrict__ zaccb,
    const float* __restrict__ scf, const int* __restrict__ sSrc,
    const int* __restrict__ sDst, const float* __restrict__ xres,
    const float* __restrict__ vvec)
{
    __shared__ __align__(16) short ldsB[16384];
    __shared__ float ldsS[128], ldsQ[128];
    int tid = threadIdx.x;
    {
        const float4* s4 = (const float4*)Bp;
        float4* d4 = (float4*)ldsB;
        #pragma unroll
        for (int i = 0; i < 8; i++) d4[tid + i * 256] = s4[tid + i * 256];
    }
    if (EPI == 2) { if (tid < 128) { ldsS[tid] = 0.f; ldsQ[tid] = 0.f; } }
    __syncthreads();

    int wave = tid >> 6, lane = tid & 63;
    int kgrp = lane >> 4, colbase = lane & 15;
    int G = gridDim.x;

    float bcol[8];
    #pragma unroll
    for (int n = 0; n < 8; n++) bcol[n] = bias[n * 16 + colbase];
    float vcol[8];
    if (EPI == 0) {
        #pragma unroll
        for (int n = 0; n < 8; n++) vcol[n] = vvec[n * 16 + colbase];
    }
    float sreg[8], qreg[8];
    if (EPI == 2) {
        #pragma unroll
        for (int n = 0; n < 8; n++) { sreg[n] = 0.f; qreg[n] = 0.f; }
    }

    bf16x8 afc[4], afn[4];
    int dstc[4], sxc[4], dstn[4], sxn[4];
    float cfc[4], cfn[4];

    int chunk = blockIdx.x;
    bool have = chunk < nch;
    if (have) {
        int rowA = chunk * 64 + wave * 16 + colbase;
        bool rv = rowA < M;
        #pragma unroll
        for (int ks = 0; ks < 4; ks++)
            afc[ks] = rv ? *(const bf16x8*)(A + (size_t)rowA * 128 + ks * 32 + kgrp * 8)
                         : (bf16x8){0,0,0,0,0,0,0,0};
        if (EPI == 3) {
            int rb = chunk * 64 + wave * 16 + kgrp * 4;
            #pragma unroll
            for (int r = 0; r < 4; r++) {
                int row = rb + r; bool ok = row < M;
                dstc[r] = ok ? sDst[row] : -1;
                sxc[r]  = ok ? sSrc[row] : 0;
                cfc[r]  = ok ? scf[row] : 0.f;
            }
        }
    }

    while (have) {
        int nxt = chunk + G;
        bool haveN = nxt < nch;
        if (haveN) {
            int rowA = nxt * 64 + wave * 16 + colbase;
            bool rv = rowA < M;
            #pragma unroll
            for (int ks = 0; ks < 4; ks++)
                afn[ks] = rv ? *(const bf16x8*)(A + (size_t)rowA * 128 + ks * 32 + kgrp * 8)
                             : (bf16x8){0,0,0,0,0,0,0,0};
            if (EPI == 3) {
                int rb = nxt * 64 + wave * 16 + kgrp * 4;
                #pragma unroll
                for (int r = 0; r < 4; r++) {
                    int row = rb + r; bool ok = row < M;
                    dstn[r] = ok ? sDst[row] : -1;
                    sxn[r]  = ok ? sSrc[row] : 0;
                    cfn[r]  = ok ? scf[row] : 0.f;
                }
            }
        }

        f32x4 acc[8];
        #pragma unroll
        for (int n = 0; n < 8; n++) acc[n] = (f32x4){0.f, 0.f, 0.f, 0.f};
        #pragma unroll
        for (int ks = 0; ks < 4; ks++) {
            #pragma unroll
            for (int n = 0; n < 8; n++) {
                bf16x8 bf = *(const bf16x8*)(ldsB + ((size_t)((n * 4 + ks) * 64 + lane)) * 8);
                acc[n] = __builtin_amdgcn_mfma_f32_16x16x32_bf16(afc[ks], bf, acc[n], 0, 0, 0);
            }
        }

        int rbase = chunk * 64 + wave * 16 + kgrp * 4;

        if (EPI == 0) {
            #pragma unroll
            for (int n = 0; n < 8; n++) {
                int col = n * 16 + colbase;
                #pragma unroll
                for (int r = 0; r < 4; r++) {
                    int row = rbase + r;
                    float val = acc[n][r] + bcol[n];
                    float zv = vcol[n] * val;
                    float pv = __shfl_xor(val, 1);
                    float pz = __shfl_xor(zv, 1);
                    if (row < M && !(lane & 1)) {
                        size_t o2 = ((size_t)row * 128 + col) >> 1;
                        ((unsigned*)out)[o2]  = packbf(val, pv);
                        ((unsigned*)out2)[o2] = packbf(zv, pz);
                    }
                }
            }
        } else if (EPI == 1) {
            #pragma unroll
            for (int n = 0; n < 8; n++) {
                int col = n * 16 + colbase;
                #pragma unroll
                for (int r = 0; r < 4; r++) {
                    int row = rbase + r;
                    float val = acc[n][r] + bcol[n];
                    float pv = __shfl_xor(val, 1);
                    if (row < M && !(lane & 1))
                        ((unsigned*)out)[((size_t)row * 128 + col) >> 1] = packbf(val, pv);
                }
            }
        } else if (EPI == 2) {
            #pragma unroll
            for (int n = 0; n < 8; n++) {
                int col = n * 16 + colbase;
                #pragma unroll
                for (int r = 0; r < 4; r++) {
                    int row = rbase + r;
                    float z = acc[n][r] + bcol[n];
                    z = z >= 0.f ? z : 0.01f * z;
                    if (row >= M) z = 0.f;
                    sreg[n] += z; qreg[n] += z * z;
                    float pz = __shfl_xor(z, 1);
                    if (row < M && !(lane & 1))
                        ((unsigned*)out)[((size_t)row * 128 + col) >> 1] = packbf(z, pz);
                }
            }
        } else if (EPI == 3) {
            #pragma unroll
            for (int n = 0; n < 8; n++) {
                int col = n * 16 + colbase;
                float run = 0.f; int curd = dstc[0];
                #pragma unroll
                for (int r = 0; r < 4; r++) {
                    float mm = 0.f;
                    if (dstc[r] >= 0) {
                        float val = acc[n][r] + bcol[n];
                        unsigned xu = 0;
                        if (!(lane & 1))
                            xu = *(const unsigned*)(xdb + (size_t)sxc[r] * 128 + col);
                        xu = __shfl(xu, lane & ~1);
                        float2 xv = bfpair(xu);
                        float xdv = (lane & 1) ? xv.y : xv.x;
                        mm = cfc[r] * val * xdv;
                    }
                    if (dstc[r] != curd) {
                        float ro = __shfl_xor(run, 1);
                        if (curd >= 0 && !(lane & 1)) {
                            unsigned packed = packbf(run, ro);
                            short* ap = zaccb + (size_t)curd * 128 + col;
                            asm volatile("global_atomic_pk_add_bf16 %0, %1, off"
                                         :: "v"(ap), "v"(packed) : "memory");
                        }
                        run = 0.f; curd = dstc[r];
                    }
                    run += mm;
                }
                float ro = __shfl_xor(run, 1);
                if (curd >= 0 && !(lane & 1)) {
                    unsigned packed = packbf(run, ro);
                    short* ap = zaccb + (size_t)curd * 128 + col;
                    asm volatile("global_atomic_pk_add_bf16 %0, %1, off"
                                 :: "v"(ap), "v"(packed) : "memory");
                }
            }
        } else if (EPI == 4) {
            float* outf = (float*)out;
            #pragma unroll
            for (int n = 0; n < 8; n++) {
                int col = n * 16 + colbase;
                #pragma unroll
                for (int r = 0; r < 4; r++) {
                    int row = rbase + r;
                    float val = acc[n][r] + bcol[n];
                    if (row < M) val += xres[(size_t)row * 128 + col];
                    float pv = __shfl_xor(val, 1);
                    if (row < M && !(lane & 1)) {
                        float2 st; st.x = val; st.y = pv;
                        *(float2*)(outf + (size_t)row * 128 + col) = st;
                    }
                }
            }
        }

        chunk = nxt; have = haveN;
        if (haveN) {
            #pragma unroll
            for (int ks = 0; ks < 4; ks++) afc[ks] = afn[ks];
            if (EPI == 3) {
                #pragma unroll
                for (int r = 0; r < 4; r++) { dstc[r] = dstn[r]; sxc[r] = sxn[r]; cfc[r] = cfn[r]; }
            }
        }
    }

    if (EPI == 2) {
        #pragma unroll
        for (int n = 0; n < 8; n++) {
            atomicAdd(&ldsS[n * 16 + colbase], sreg[n]);
            atomicAdd(&ldsQ[n * 16 + colbase], qreg[n]);
        }
        __syncthreads();
        if (tid < 128) {
            int rep = blockIdx.x & 15;
            atomicAdd(&stats[rep * 256 + tid], ldsS[tid]);
            atomicAdd(&stats[rep * 256 + 128 + tid], ldsQ[tid]);
        }
    }
}

extern "C" void kernel_launch(void* const* d_in, const int* in_sizes, int n_in,
                              void* d_out, int out_size, void* d_ws, size_t ws_size,
                              hipStream_t stream)
{
    const float* x    = (const float*)d_in[0];
    const float* ea   = (const float*)d_in[1];
    const int*   eidx = (const int*)d_in[2];
    const float* Wb   = (const float*)d_in[3];
    const float* bb   = (const float*)d_in[4];
    const float* We1  = (const float*)d_in[5];
    const float* be1  = (const float*)d_in[6];
    const float* ge1  = (const float*)d_in[7];
    const float* bte1 = (const float*)d_in[8];
    const float* We2  = (const float*)d_in[9];
    const float* be2  = (const float*)d_in[10];
    const float* ge2  = (const float*)d_in[11];
    const float* bte2 = (const float*)d_in[12];
    const float* We3  = (const float*)d_in[13];
    const float* be3  = (const float*)d_in[14];
    const float* Wd   = (const float*)d_in[15];
    const float* bd   = (const float*)d_in[16];
    const float* vv   = (const float*)d_in[17];
    const float* Wn1  = (const float*)d_in[18];
    const float* bn1  = (const float*)d_in[19];
    const float* gn   = (const float*)d_in[20];
    const float* btn  = (const float*)d_in[21];
    const float* Wn2  = (const float*)d_in[22];
    const float* bn2  = (const float*)d_in[23];

    const int NN = in_sizes[0] / 128;   // 50000
    const int EE = in_sizes[1] / 4;     // 300000

    char* ws = (char*)d_ws;
    size_t oEZ   = 0;
    size_t oXD   = oEZ   + (size_t)EE * 256;
    size_t oXS   = oXD   + (size_t)NN * 256;
    size_t oXT   = oXS   + (size_t)NN * 256;
    size_t oZACC = oXT   + (size_t)NN * 256;
    size_t oZN   = oZACC + (size_t)NN * 256;
    size_t oXB   = oZN   + (size_t)NN * 256;
    size_t oTAB  = oXB   + (size_t)NN * 256;
    size_t oW1P  = oTAB  + (size_t)4 * 1025 * 256;
    size_t oB1P  = oW1P  + (size_t)200 * 512;
    size_t oBP   = oB1P  + 512;
    size_t oBIAS = oBP   + (size_t)7 * 32768;
    size_t oST   = oBIAS + (size_t)7 * 512;
    size_t oCNT  = oST   + 49152;
    size_t oPOS  = oCNT  + 201728;
    size_t oBSUM = oPOS  + 201728;
    size_t oPOS2 = oBSUM + 1024;
    size_t oSSRC = oPOS2 + 201728;
    size_t oSDST = oSSRC + (size_t)EE * 4;
    size_t oSCF  = oSDST + (size_t)EE * 4;
    size_t oSEA  = (oSCF + (size_t)EE * 4 + 15) & ~(size_t)15;

    short* eZ    = (short*)(ws + oEZ);
    short* xdb   = (short*)(ws + oXD);
    short* xs1b  = (short*)(ws + oXS);
    short* xt1b  = (short*)(ws + oXT);
    short* zaccb = (short*)(ws + oZACC);
    short* zn    = (short*)(ws + oZN);
    short* xb    = (short*)(ws + oXB);
    short* tab   = (short*)(ws + oTAB);
    float* W1p   = (float*)(ws + oW1P);
    float* b1p   = (float*)(ws + oB1P);
    short* bp    = (short*)(ws + oBP);
    short* BpW2  = bp + 3 * 16384;
    short* BpW3  = bp + 4 * 16384;
    short* BpN1  = bp + 5 * 16384;
    short* BpN2  = bp + 6 * 16384;
    float* bo    = (float*)(ws + oBIAS);
    float* b2p   = bo + 0 * 128;
    float* b3p   = bo + 1 * 128;
    float* b2np  = bo + 2 * 128;
    float* bz    = bo + 3 * 128;   // zero bias for EPI1 passes
    float* st1   = (float*)(ws + oST);
    float* st2   = st1 + 4096;
    float* stN   = st1 + 8192;
    int*   cnt   = (int*)(ws + oCNT);
    int*   posE  = (int*)(ws + oPOS);
    int*   bsum  = (int*)(ws + oBSUM);
    int*   pos2  = (int*)(ws + oPOS2);
    int*   sSrc  = (int*)(ws + oSSRC);
    int*   sDst  = (int*)(ws + oSDST);
    float* scf   = (float*)(ws + oSCF);
    float4* sEa  = (float4*)(ws + oSEA);

    // zero stats (48KB) + zero-bias slot (512B within bias block) + cnt (197KB)
    hipMemsetAsync(bz, 0, 512, stream);
    hipMemsetAsync(ws + oST, 0, 49152 + 201728, stream);

    build_w1p_k<<<201, 128, 0, stream>>>(Wb, We1, bb, be1, W1p, b1p);
    build_tab_k<<<dim3(1025, 4), 128, 0, stream>>>(W1p, b1p, tab);
    fold_plain_k<<<dim3(8, 4), 256, 0, stream>>>(
        Wd, We1, We1 + 256 * 128, Wn1, bp, bp + 16384, bp + 2 * 16384, BpN1);

    int nchN = (NN + 63) / 64;
    int nchE = (EE + 63) / 64;
    int GN = nchN < 1024 ? nchN : 1024;
    int GE = nchE < 1024 ? nchE : 1024;
    int nbN = (NN + 255) / 256;
    int nbE = (EE + 255) / 256;

    cast_k<<<(NN * 128 / 8 + 255) / 256, 256, 0, stream>>>(x, (unsigned*)xb, NN * 128 / 8);

    // node precompute: xd/zacc, xs1, xt1
    pgemm_k<0><<<GN, 256, 0, stream>>>(xb, NN, nchN, bp, bd, xdb, zaccb, nullptr,
                                       nullptr, nullptr, nullptr, nullptr, nullptr, nullptr, vv);
    pgemm_k<1><<<GN, 256, 0, stream>>>(xb, NN, nchN, bp + 16384, bz, xs1b, nullptr, nullptr,
                                       nullptr, nullptr, nullptr, nullptr, nullptr, nullptr, nullptr);
    pgemm_k<1><<<GN, 256, 0, stream>>>(xb, NN, nchN, bp + 2 * 16384, bz, xt1b, nullptr, nullptr,
                                       nullptr, nullptr, nullptr, nullptr, nullptr, nullptr, nullptr);

    // counting sort by dst
    hist_k<<<nbE, 256, 0, stream>>>(eidx + EE, cnt, EE);
    scan1_k<<<nbN, 256, 0, stream>>>(cnt, NN, posE, bsum);
    scan2_k<<<1, 256, 0, stream>>>(bsum, nbN);
    fix_k<<<nbN, 256, 0, stream>>>(posE, bsum, pos2, NN);
    scat_k<<<nbE, 256, 0, stream>>>(eidx, eidx + EE, (const float4*)ea, pos2,
                                    sSrc, sDst, scf, sEa, EE);

    edge_z1_k<<<nbE, 256, 0, stream>>>(xs1b, xt1b, tab, sSrc, sDst, sEa, eZ, st1, EE);

    fold_k<<<8, 256, 0, stream>>>(We2, be2, st1, ge1, bte1, 1.f / (float)EE, BpW2, b2p);
    pgemm_k<2><<<GE, 256, 0, stream>>>(eZ, EE, nchE, BpW2, b2p, eZ, nullptr, st2,
                                       nullptr, nullptr, nullptr, nullptr, nullptr, nullptr, nullptr);

    fold_k<<<8, 256, 0, stream>>>(We3, be3, st2, ge2, bte2, 1.f / (float)EE, BpW3, b3p);
    pgemm_k<3><<<GE, 256, 0, stream>>>(eZ, EE, nchE, BpW3, b3p, nullptr, nullptr, nullptr,
                                       xdb, zaccb, scf, sSrc, sDst, nullptr, nullptr);

    pgemm_k<2><<<GN, 256, 0, stream>>>(zaccb, NN, nchN, BpN1, bn1, zn, nullptr, stN,
                                       nullptr, nullptr, nullptr, nullptr, nullptr, nullptr, nullptr);

    fold_k<<<8, 256, 0, stream>>>(Wn2, bn2, stN, gn, btn, 1.f / (float)NN, BpN2, b2np);
    pgemm_k<4><<<GN, 256, 0, stream>>>(zn, NN, nchN, BpN2, b2np, d_out, nullptr, nullptr,
                                       nullptr, nullptr, nullptr, nullptr, nullptr, x, nullptr);
}

// Round 5
// 573.476 us; speedup vs baseline: 1.0531x; 1.0531x over previous
//
#include <hip/hip_runtime.h>

typedef __attribute__((ext_vector_type(8))) short bf16x8;
typedef __attribute__((ext_vector_type(4))) float f32x4;

#define DEVFN __device__ __forceinline__

DEVFN short f2bf(float f) {
    union { float f; unsigned u; } v; v.f = f;
    unsigned r = (v.u + 0x7FFFu + ((v.u >> 16) & 1u)) >> 16;
    return (short)(unsigned short)r;
}
DEVFN float bf2f(short h) {
    union { unsigned u; float f; } v; v.u = ((unsigned)(unsigned short)h) << 16;
    return v.f;
}
DEVFN float2 bfpair(unsigned u) {
    union { unsigned v; float f; } a, b;
    a.v = u << 16; b.v = u & 0xFFFF0000u;
    float2 r; r.x = a.f; r.y = b.f; return r;
}
DEVFN unsigned packbf(float a, float b) {
    return (unsigned)(unsigned short)f2bf(a) | ((unsigned)(unsigned short)f2bf(b) << 16);
}

// ---------------- prep kernels ----------------

__global__ __launch_bounds__(128) void build_w1p_k(
    const float* __restrict__ Wb, const float* __restrict__ We1,
    const float* __restrict__ bb, const float* __restrict__ be1,
    float* __restrict__ W1p, float* __restrict__ b1p)
{
    int j = threadIdx.x;
    const float* B = We1 + 128 * 128;
    int i = blockIdx.x;
    if (i < 200) {
        float a = 0.f;
        for (int m = 0; m < 128; m++) a += Wb[i * 128 + m] * B[m * 128 + j];
        W1p[i * 128 + j] = a;
    } else {
        float a = be1[j];
        for (int m = 0; m < 128; m++) a += bb[m] * B[m * 128 + j];
        b1p[j] = a;
    }
}

__global__ __launch_bounds__(128) void build_tab_k(
    const float* __restrict__ W1p, const float* __restrict__ b1p,
    short* __restrict__ tab)
{
    int i = blockIdx.x;   // 0..1024
    int c = blockIdx.y;   // 0..3
    int j = threadIdx.x;
    float t = (float)i * (1.0f / 1024.0f);
    float acc = (c == 0) ? b1p[j] : 0.f;
    int kc = (int)(t * 49.f + 0.5f);
    for (int dk = -6; dk <= 6; dk++) {
        int k = kc + dk;
        if (k >= 0 && k < 50) {
            float d = t - (float)k * (1.f / 49.f);
            float g = expf(-1250.f * d * d);
            acc += g * W1p[(c * 50 + k) * 128 + j];
        }
    }
    tab[((size_t)(c * 1025 + i)) * 128 + j] = f2bf(acc);
}

__global__ __launch_bounds__(256) void fold_plain_k(
    const float* __restrict__ W0, const float* __restrict__ W1,
    const float* __restrict__ W2, const float* __restrict__ W3,
    short* __restrict__ O0, short* __restrict__ O1,
    short* __restrict__ O2, short* __restrict__ O3)
{
    const float* W = (blockIdx.y == 0) ? W0 : (blockIdx.y == 1) ? W1 : (blockIdx.y == 2) ? W2 : W3;
    short* O = (blockIdx.y == 0) ? O0 : (blockIdx.y == 1) ? O1 : (blockIdx.y == 2) ? O2 : O3;
    int idx = blockIdx.x * 256 + threadIdx.x;
    int n = idx >> 8, ks = (idx >> 6) & 3, lane = idx & 63;
    int k8 = ks * 32 + (lane >> 4) * 8;
    int col = n * 16 + (lane & 15);
    bf16x8 fv;
    #pragma unroll
    for (int i2 = 0; i2 < 8; i2++) fv[i2] = f2bf(W[(k8 + i2) * 128 + col]);
    *(bf16x8*)(O + (size_t)idx * 8) = fv;
}

__global__ __launch_bounds__(256) void fold_k(
    const float* __restrict__ W, const float* __restrict__ bias,
    const float* __restrict__ statsG, const float* __restrict__ gamma,
    const float* __restrict__ beta, float invNs,
    short* __restrict__ Bp, float* __restrict__ biasOut)
{
    __shared__ float sS[128], sT[128];
    int tid = threadIdx.x;
    if (tid < 128) {
        float sum = 0.f, sq = 0.f;
        for (int r = 0; r < 16; r++) {
            sum += statsG[r * 256 + tid];
            sq  += statsG[r * 256 + 128 + tid];
        }
        float m = sum * invNs;
        float var = sq * invNs - m * m;
        float rs = rsqrtf(var + 1e-5f);
        float s = rs * gamma[tid];
        float t = beta[tid] - m * s;
        sS[tid] = s; sT[tid] = t;
    }
    __syncthreads();
    if (blockIdx.x == 0 && tid < 128) {
        float b = bias[tid];
        for (int k = 0; k < 128; k++) b += sT[k] * W[k * 128 + tid];
        biasOut[tid] = b;
    }
    int idx = blockIdx.x * 256 + tid;
    int n = idx >> 8, ks = (idx >> 6) & 3, lane = idx & 63;
    int k8 = ks * 32 + (lane >> 4) * 8;
    int col = n * 16 + (lane & 15);
    bf16x8 fv;
    #pragma unroll
    for (int i2 = 0; i2 < 8; i2++)
        fv[i2] = f2bf(sS[k8 + i2] * W[(k8 + i2) * 128 + col]);
    *(bf16x8*)(Bp + (size_t)idx * 8) = fv;
}

// ---------------- x -> bf16 cast ----------------
__global__ __launch_bounds__(256) void cast_k(
    const float* __restrict__ x, unsigned* __restrict__ xb2, int n8)
{
    int i = blockIdx.x * 256 + threadIdx.x;
    if (i >= n8) return;
    const float4* p = (const float4*)x + (size_t)i * 2;
    float4 a = p[0], b = p[1];
    uint4 o;
    o.x = packbf(a.x, a.y); o.y = packbf(a.z, a.w);
    o.z = packbf(b.x, b.y); o.w = packbf(b.z, b.w);
    ((uint4*)xb2)[i] = o;
}

// ---------------- counting sort by dst ----------------

__global__ __launch_bounds__(256) void hist_k(
    const int* __restrict__ dstI, int* __restrict__ cnt, int E)
{
    int e = blockIdx.x * 256 + threadIdx.x;
    if (e < E) atomicAdd(&cnt[dstI[e]], 1);
}

__global__ __launch_bounds__(256) void scan1_k(
    const int* __restrict__ cnt, int Nn, int* __restrict__ posE, int* __restrict__ bsum)
{
    __shared__ int s[256];
    int t = threadIdx.x, g = blockIdx.x * 256 + t;
    int v = (g < Nn) ? cnt[g] : 0;
    s[t] = v;
    __syncthreads();
    for (int off = 1; off < 256; off <<= 1) {
        int u = (t >= off) ? s[t - off] : 0;
        __syncthreads();
        s[t] += u;
        __syncthreads();
    }
    if (g < Nn) posE[g] = s[t] - v;
    if (t == 255) bsum[blockIdx.x] = s[255];
}

__global__ __launch_bounds__(256) void scan2_k(int* __restrict__ bsum, int nb)
{
    __shared__ int s[256];
    int t = threadIdx.x;
    int v = (t < nb) ? bsum[t] : 0;
    s[t] = v;
    __syncthreads();
    for (int off = 1; off < 256; off <<= 1) {
        int u = (t >= off) ? s[t - off] : 0;
        __syncthreads();
        s[t] += u;
        __syncthreads();
    }
    if (t < nb) bsum[t] = s[t] - v;
}

__global__ __launch_bounds__(256) void fix_k(
    const int* __restrict__ posE, const int* __restrict__ bsum,
    int* __restrict__ pos2, int Nn)
{
    int id = blockIdx.x * 256 + threadIdx.x;
    if (id < Nn) pos2[id] = posE[id] + bsum[id >> 8];
}

__global__ __launch_bounds__(256) void scat_k(
    const int* __restrict__ srcI, const int* __restrict__ dstI,
    const float4* __restrict__ ea4, int* __restrict__ pos2,
    int* __restrict__ sSrc, int* __restrict__ sDst,
    float* __restrict__ scf, float4* __restrict__ sEa, int E)
{
    int e = blockIdx.x * 256 + threadIdx.x;
    if (e >= E) return;
    int d = dstI[e];
    int p = atomicAdd(&pos2[d], 1);
    sSrc[p] = srcI[e];
    sDst[p] = d;
    float4 ev = ea4[e];
    sEa[p] = ev;
    scf[p] = cosf(1.57079632679f * ev.w);
}

// ---------------- edge pass 1 (sorted order, 2 cols/lane) ----------------
__global__ __launch_bounds__(256) void edge_z1_k(
    const short* __restrict__ xs1b, const short* __restrict__ xt1b,
    const short* __restrict__ tab,
    const int* __restrict__ sSrc, const int* __restrict__ sDst,
    const float4* __restrict__ sEa,
    short* __restrict__ z1, float* __restrict__ stats, int Etot)
{
    int tid = threadIdx.x, wave = tid >> 6, lane = tid & 63;
    int e0 = blockIdx.x * 256 + wave * 64;
    const unsigned* xs2 = (const unsigned*)xs1b;
    const unsigned* xt2 = (const unsigned*)xt1b;
    const unsigned* tb2 = (const unsigned*)tab;
    unsigned* z2 = (unsigned*)z1;

    int eL = e0 + lane;
    int myS = 0, myD = 0;
    float4 myE = {0.f, 0.f, 0.f, 0.f};
    if (eL < Etot) { myS = sSrc[eL]; myD = sDst[eL]; myE = sEa[eL]; }

    float s0 = 0.f, q0 = 0.f, s1 = 0.f, q1 = 0.f;
    int ni = Etot - e0; if (ni > 64) ni = 64;
    for (int i = 0; i < ni; i++) {
        int s = __shfl(myS, i), d = __shfl(myD, i);
        float tv[4];
        tv[0] = __shfl(myE.x, i); tv[1] = __shfl(myE.y, i);
        tv[2] = __shfl(myE.z, i); tv[3] = __shfl(myE.w, i);
        float2 xs = bfpair(xs2[(size_t)s * 64 + lane]);
        float2 xt = bfpair(xt2[(size_t)d * 64 + lane]);
        float p0 = xs.x + xt.x, p1 = xs.y + xt.y;
        #pragma unroll
        for (int c = 0; c < 4; c++) {
            float u = tv[c] * 1024.f;
            int i0 = (int)u;
            if (i0 > 1023) i0 = 1023;
            if (i0 < 0) i0 = 0;
            float f = u - (float)i0;
            size_t base = (size_t)(c * 1025 + i0) * 64 + lane;
            float2 v0 = bfpair(tb2[base]);
            float2 v1 = bfpair(tb2[base + 64]);
            p0 += v0.x + f * (v1.x - v0.x);
            p1 += v0.y + f * (v1.y - v0.y);
        }
        float z0 = p0 >= 0.f ? p0 : 0.01f * p0;
        float z1v = p1 >= 0.f ? p1 : 0.01f * p1;
        z2[(size_t)(e0 + i) * 64 + lane] = packbf(z0, z1v);
        s0 += z0; q0 += z0 * z0; s1 += z1v; q1 += z1v * z1v;
    }

    __shared__ float lS[128], lQ[128];
    if (tid < 128) { lS[tid] = 0.f; lQ[tid] = 0.f; }
    __syncthreads();
    atomicAdd(&lS[2 * lane], s0);     atomicAdd(&lS[2 * lane + 1], s1);
    atomicAdd(&lQ[2 * lane], q0);     atomicAdd(&lQ[2 * lane + 1], q1);
    __syncthreads();
    if (tid < 128) {
        int rep = blockIdx.x & 15;
        atomicAdd(&stats[rep * 256 + tid], lS[tid]);
        atomicAdd(&stats[rep * 256 + 128 + tid], lQ[tid]);
    }
}

// ---------------- batched tall-skinny MFMA GEMM ----------------
// Block handles NB chunks of 64 rows; ALL NB*4 A-fragments preloaded up front
// (deep vmem ILP hides the ~900cyc load latency), then per-chunk MFMA+epilogue.
// EPI 0: out=bf16 val (xd);  out2 = bf16 v*val (zacc init)
// EPI 1: out=bf16 val
// EPI 2: z=lrelu(val); out bf16; BN stats (register-accumulated)
// EPI 3: dst-sorted scatter: run-merged pk_add_bf16(zacc[dst], cf*val*xd[src])
// EPI 4: out fp32 = val + xres
template<int EPI, int NB>
__global__ __launch_bounds__(256, 3) void pgemm_k(
    const short* __restrict__ A, int M,
    const short* __restrict__ Bp, const float* __restrict__ bias,
    void* __restrict__ out, short* __restrict__ out2,
    float* __restrict__ stats,
    const short* __restrict__ xdb, short* __restrict__ zaccb,
    const float* __restrict__ scf, const int* __restrict__ sSrc,
    const int* __restrict__ sDst, const float* __restrict__ xres,
    const float* __restrict__ vvec)
{
    __shared__ __align__(16) short ldsB[16384];
    __shared__ float ldsS[128], ldsQ[128];
    int tid = threadIdx.x;
    {
        const float4* s4 = (const float4*)Bp;
        float4* d4 = (float4*)ldsB;
        #pragma unroll
        for (int i = 0; i < 8; i++) d4[tid + i * 256] = s4[tid + i * 256];
    }
    if (EPI == 2) { if (tid < 128) { ldsS[tid] = 0.f; ldsQ[tid] = 0.f; } }
    __syncthreads();

    int wave = tid >> 6, lane = tid & 63;
    int kgrp = lane >> 4, colbase = lane & 15;
    int c0 = blockIdx.x * NB;

    // deep preload: A fragments for all NB chunks
    bf16x8 af[NB][4];
    #pragma unroll
    for (int j = 0; j < NB; j++) {
        int rowA = (c0 + j) * 64 + wave * 16 + colbase;
        bool rv = rowA < M;
        #pragma unroll
        for (int ks = 0; ks < 4; ks++)
            af[j][ks] = rv ? *(const bf16x8*)(A + (size_t)rowA * 128 + ks * 32 + kgrp * 8)
                           : (bf16x8){0,0,0,0,0,0,0,0};
    }
    // EPI3 metadata preload
    int mdst[NB][4], msx[NB][4]; float mcf[NB][4];
    if (EPI == 3) {
        #pragma unroll
        for (int j = 0; j < NB; j++) {
            int rb = (c0 + j) * 64 + wave * 16 + kgrp * 4;
            #pragma unroll
            for (int r = 0; r < 4; r++) {
                int row = rb + r; bool ok = row < M;
                mdst[j][r] = ok ? sDst[row] : -1;
                msx[j][r]  = ok ? sSrc[row] : 0;
                mcf[j][r]  = ok ? scf[row] : 0.f;
            }
        }
    }

    float bcol[8];
    #pragma unroll
    for (int n = 0; n < 8; n++) bcol[n] = bias[n * 16 + colbase];
    float vcol[8];
    if (EPI == 0) {
        #pragma unroll
        for (int n = 0; n < 8; n++) vcol[n] = vvec[n * 16 + colbase];
    }
    float sreg[8], qreg[8];
    if (EPI == 2) {
        #pragma unroll
        for (int n = 0; n < 8; n++) { sreg[n] = 0.f; qreg[n] = 0.f; }
    }

    #pragma unroll
    for (int j = 0; j < NB; j++) {
        int chunk = c0 + j;
        if (chunk * 64 >= M) break;

        f32x4 acc[8];
        #pragma unroll
        for (int n = 0; n < 8; n++) acc[n] = (f32x4){0.f, 0.f, 0.f, 0.f};
        #pragma unroll
        for (int ks = 0; ks < 4; ks++) {
            #pragma unroll
            for (int n = 0; n < 8; n++) {
                bf16x8 bf = *(const bf16x8*)(ldsB + ((size_t)((n * 4 + ks) * 64 + lane)) * 8);
                acc[n] = __builtin_amdgcn_mfma_f32_16x16x32_bf16(af[j][ks], bf, acc[n], 0, 0, 0);
            }
        }

        int rbase = chunk * 64 + wave * 16 + kgrp * 4;

        if (EPI == 0) {
            #pragma unroll
            for (int n = 0; n < 8; n++) {
                int col = n * 16 + colbase;
                #pragma unroll
                for (int r = 0; r < 4; r++) {
                    int row = rbase + r;
                    float val = acc[n][r] + bcol[n];
                    float zv = vcol[n] * val;
                    float pv = __shfl_xor(val, 1);
                    float pz = __shfl_xor(zv, 1);
                    if (row < M && !(lane & 1)) {
                        size_t o2 = ((size_t)row * 128 + col) >> 1;
                        ((unsigned*)out)[o2]  = packbf(val, pv);
                        ((unsigned*)out2)[o2] = packbf(zv, pz);
                    }
                }
            }
        } else if (EPI == 1) {
            #pragma unroll
            for (int n = 0; n < 8; n++) {
                int col = n * 16 + colbase;
                #pragma unroll
                for (int r = 0; r < 4; r++) {
                    int row = rbase + r;
                    float val = acc[n][r] + bcol[n];
                    float pv = __shfl_xor(val, 1);
                    if (row < M && !(lane & 1))
                        ((unsigned*)out)[((size_t)row * 128 + col) >> 1] = packbf(val, pv);
                }
            }
        } else if (EPI == 2) {
            #pragma unroll
            for (int n = 0; n < 8; n++) {
                int col = n * 16 + colbase;
                #pragma unroll
                for (int r = 0; r < 4; r++) {
                    int row = rbase + r;
                    float z = acc[n][r] + bcol[n];
                    z = z >= 0.f ? z : 0.01f * z;
                    if (row >= M) z = 0.f;
                    sreg[n] += z; qreg[n] += z * z;
                    float pz = __shfl_xor(z, 1);
                    if (row < M && !(lane & 1))
                        ((unsigned*)out)[((size_t)row * 128 + col) >> 1] = packbf(z, pz);
                }
            }
        } else if (EPI == 3) {
            #pragma unroll
            for (int n = 0; n < 8; n++) {
                int col = n * 16 + colbase;
                float run = 0.f; int curd = mdst[j][0];
                #pragma unroll
                for (int r = 0; r < 4; r++) {
                    float mm = 0.f;
                    if (mdst[j][r] >= 0) {
                        float val = acc[n][r] + bcol[n];
                        unsigned xu = 0;
                        if (!(lane & 1))
                            xu = *(const unsigned*)(xdb + (size_t)msx[j][r] * 128 + col);
                        xu = __shfl(xu, lane & ~1);
                        float2 xv = bfpair(xu);
                        float xdv = (lane & 1) ? xv.y : xv.x;
                        mm = mcf[j][r] * val * xdv;
                    }
                    if (mdst[j][r] != curd) {
                        float ro = __shfl_xor(run, 1);
                        if (curd >= 0 && !(lane & 1)) {
                            unsigned packed = packbf(run, ro);
                            short* ap = zaccb + (size_t)curd * 128 + col;
                            asm volatile("global_atomic_pk_add_bf16 %0, %1, off"
                                         :: "v"(ap), "v"(packed) : "memory");
                        }
                        run = 0.f; curd = mdst[j][r];
                    }
                    run += mm;
                }
                float ro = __shfl_xor(run, 1);
                if (curd >= 0 && !(lane & 1)) {
                    unsigned packed = packbf(run, ro);
                    short* ap = zaccb + (size_t)curd * 128 + col;
                    asm volatile("global_atomic_pk_add_bf16 %0, %1, off"
                                 :: "v"(ap), "v"(packed) : "memory");
                }
            }
        } else if (EPI == 4) {
            float* outf = (float*)out;
            #pragma unroll
            for (int n = 0; n < 8; n++) {
                int col = n * 16 + colbase;
                #pragma unroll
                for (int r = 0; r < 4; r++) {
                    int row = rbase + r;
                    float val = acc[n][r] + bcol[n];
                    if (row < M) val += xres[(size_t)row * 128 + col];
                    float pv = __shfl_xor(val, 1);
                    if (row < M && !(lane & 1)) {
                        float2 st; st.x = val; st.y = pv;
                        *(float2*)(outf + (size_t)row * 128 + col) = st;
                    }
                }
            }
        }
    }

    if (EPI == 2) {
        #pragma unroll
        for (int n = 0; n < 8; n++) {
            atomicAdd(&ldsS[n * 16 + colbase], sreg[n]);
            atomicAdd(&ldsQ[n * 16 + colbase], qreg[n]);
        }
        __syncthreads();
        if (tid < 128) {
            int rep = blockIdx.x & 15;
            atomicAdd(&stats[rep * 256 + tid], ldsS[tid]);
            atomicAdd(&stats[rep * 256 + 128 + tid], ldsQ[tid]);
        }
    }
}

extern "C" void kernel_launch(void* const* d_in, const int* in_sizes, int n_in,
                              void* d_out, int out_size, void* d_ws, size_t ws_size,
                              hipStream_t stream)
{
    const float* x    = (const float*)d_in[0];
    const float* ea   = (const float*)d_in[1];
    const int*   eidx = (const int*)d_in[2];
    const float* Wb   = (const float*)d_in[3];
    const float* bb   = (const float*)d_in[4];
    const float* We1  = (const float*)d_in[5];
    const float* be1  = (const float*)d_in[6];
    const float* ge1  = (const float*)d_in[7];
    const float* bte1 = (const float*)d_in[8];
    const float* We2  = (const float*)d_in[9];
    const float* be2  = (const float*)d_in[10];
    const float* ge2  = (const float*)d_in[11];
    const float* bte2 = (const float*)d_in[12];
    const float* We3  = (const float*)d_in[13];
    const float* be3  = (const float*)d_in[14];
    const float* Wd   = (const float*)d_in[15];
    const float* bd   = (const float*)d_in[16];
    const float* vv   = (const float*)d_in[17];
    const float* Wn1  = (const float*)d_in[18];
    const float* bn1  = (const float*)d_in[19];
    const float* gn   = (const float*)d_in[20];
    const float* btn  = (const float*)d_in[21];
    const float* Wn2  = (const float*)d_in[22];
    const float* bn2  = (const float*)d_in[23];

    const int NN = in_sizes[0] / 128;   // 50000
    const int EE = in_sizes[1] / 4;     // 300000

    char* ws = (char*)d_ws;
    size_t oEZ   = 0;
    size_t oXD   = oEZ   + (size_t)EE * 256;
    size_t oXS   = oXD   + (size_t)NN * 256;
    size_t oXT   = oXS   + (size_t)NN * 256;
    size_t oZACC = oXT   + (size_t)NN * 256;
    size_t oZN   = oZACC + (size_t)NN * 256;
    size_t oXB   = oZN   + (size_t)NN * 256;
    size_t oTAB  = oXB   + (size_t)NN * 256;
    size_t oW1P  = oTAB  + (size_t)4 * 1025 * 256;
    size_t oB1P  = oW1P  + (size_t)200 * 512;
    size_t oBP   = oB1P  + 512;
    size_t oBIAS = oBP   + (size_t)7 * 32768;
    size_t oST   = oBIAS + (size_t)7 * 512;
    size_t oCNT  = oST   + 49152;
    size_t oPOS  = oCNT  + 201728;
    size_t oBSUM = oPOS  + 201728;
    size_t oPOS2 = oBSUM + 1024;
    size_t oSSRC = oPOS2 + 201728;
    size_t oSDST = oSSRC + (size_t)EE * 4;
    size_t oSCF  = oSDST + (size_t)EE * 4;
    size_t oSEA  = (oSCF + (size_t)EE * 4 + 15) & ~(size_t)15;

    short* eZ    = (short*)(ws + oEZ);
    short* xdb   = (short*)(ws + oXD);
    short* xs1b  = (short*)(ws + oXS);
    short* xt1b  = (short*)(ws + oXT);
    short* zaccb = (short*)(ws + oZACC);
    short* zn    = (short*)(ws + oZN);
    short* xb    = (short*)(ws + oXB);
    short* tab   = (short*)(ws + oTAB);
    float* W1p   = (float*)(ws + oW1P);
    float* b1p   = (float*)(ws + oB1P);
    short* bp    = (short*)(ws + oBP);
    short* BpW2  = bp + 3 * 16384;
    short* BpW3  = bp + 4 * 16384;
    short* BpN1  = bp + 5 * 16384;
    short* BpN2  = bp + 6 * 16384;
    float* bo    = (float*)(ws + oBIAS);
    float* b2p   = bo + 0 * 128;
    float* b3p   = bo + 1 * 128;
    float* b2np  = bo + 2 * 128;
    float* bz    = bo + 3 * 128;   // zero bias
    float* st1   = (float*)(ws + oST);
    float* st2   = st1 + 4096;
    float* stN   = st1 + 8192;
    int*   cnt   = (int*)(ws + oCNT);
    int*   posE  = (int*)(ws + oPOS);
    int*   bsum  = (int*)(ws + oBSUM);
    int*   pos2  = (int*)(ws + oPOS2);
    int*   sSrc  = (int*)(ws + oSSRC);
    int*   sDst  = (int*)(ws + oSDST);
    float* scf   = (float*)(ws + oSCF);
    float4* sEa  = (float4*)(ws + oSEA);

    hipMemsetAsync(bz, 0, 512, stream);
    hipMemsetAsync(ws + oST, 0, 49152 + 201728, stream);

    build_w1p_k<<<201, 128, 0, stream>>>(Wb, We1, bb, be1, W1p, b1p);
    build_tab_k<<<dim3(1025, 4), 128, 0, stream>>>(W1p, b1p, tab);
    fold_plain_k<<<dim3(8, 4), 256, 0, stream>>>(
        Wd, We1, We1 + 256 * 128, Wn1, bp, bp + 16384, bp + 2 * 16384, BpN1);

    int nchN = (NN + 63) / 64;
    int nchE = (EE + 63) / 64;
    int nbN = (NN + 255) / 256;
    int nbE = (EE + 255) / 256;

    cast_k<<<(NN * 128 / 8 + 255) / 256, 256, 0, stream>>>(x, (unsigned*)xb, NN * 128 / 8);

    // node precompute: xd/zacc (EPI0), xs1, xt1 (EPI1)
    pgemm_k<0, 2><<<(nchN + 1) / 2, 256, 0, stream>>>(xb, NN, bp, bd, xdb, zaccb, nullptr,
        nullptr, nullptr, nullptr, nullptr, nullptr, nullptr, vv);
    pgemm_k<1, 2><<<(nchN + 1) / 2, 256, 0, stream>>>(xb, NN, bp + 16384, bz, xs1b, nullptr, nullptr,
        nullptr, nullptr, nullptr, nullptr, nullptr, nullptr, nullptr);
    pgemm_k<1, 2><<<(nchN + 1) / 2, 256, 0, stream>>>(xb, NN, bp + 2 * 16384, bz, xt1b, nullptr, nullptr,
        nullptr, nullptr, nullptr, nullptr, nullptr, nullptr, nullptr);

    // counting sort by dst
    hist_k<<<nbE, 256, 0, stream>>>(eidx + EE, cnt, EE);
    scan1_k<<<nbN, 256, 0, stream>>>(cnt, NN, posE, bsum);
    scan2_k<<<1, 256, 0, stream>>>(bsum, nbN);
    fix_k<<<nbN, 256, 0, stream>>>(posE, bsum, pos2, NN);
    scat_k<<<nbE, 256, 0, stream>>>(eidx, eidx + EE, (const float4*)ea, pos2,
                                    sSrc, sDst, scf, sEa, EE);

    edge_z1_k<<<nbE, 256, 0, stream>>>(xs1b, xt1b, tab, sSrc, sDst, sEa, eZ, st1, EE);

    fold_k<<<8, 256, 0, stream>>>(We2, be2, st1, ge1, bte1, 1.f / (float)EE, BpW2, b2p);
    pgemm_k<2, 4><<<(nchE + 3) / 4, 256, 0, stream>>>(eZ, EE, BpW2, b2p, eZ, nullptr, st2,
        nullptr, nullptr, nullptr, nullptr, nullptr, nullptr, nullptr);

    fold_k<<<8, 256, 0, stream>>>(We3, be3, st2, ge2, bte2, 1.f / (float)EE, BpW3, b3p);
    pgemm_k<3, 2><<<(nchE + 1) / 2, 256, 0, stream>>>(eZ, EE, BpW3, b3p, nullptr, nullptr, nullptr,
        xdb, zaccb, scf, sSrc, sDst, nullptr, nullptr);

    pgemm_k<2, 2><<<(nchN + 1) / 2, 256, 0, stream>>>(zaccb, NN, BpN1, bn1, zn, nullptr, stN,
        nullptr, nullptr, nullptr, nullptr, nullptr, nullptr, nullptr);

    fold_k<<<8, 256, 0, stream>>>(Wn2, bn2, stN, gn, btn, 1.f / (float)NN, BpN2, b2np);
    pgemm_k<4, 2><<<(nchN + 1) / 2, 256, 0, stream>>>(zn, NN, BpN2, b2np, d_out, nullptr, nullptr,
        nullptr, nullptr, nullptr, nullptr, nullptr, x, nullptr);
}